// Round 1
// baseline (15689.897 us; speedup 1.0000x reference)
//
#include <hip/hip_runtime.h>

#define N_NEUR 4096
#define B_SZ   64
#define T_STEPS 128
#define N_CLS  10

// ---------------- Kernel A: fp64 partial GEMM ----------------
// pbuf[ks][b][n] = sum_{m in K-slice ks} s[b][m] * W_res[n][m]
#define TN 32   // neurons per workgroup
#define CH 64   // K chunk staged in LDS
#define KSL (N_NEUR / 2)

__global__ __launch_bounds__(256) void kernA(const float* __restrict__ Wres,
                                             const float* __restrict__ s_in,
                                             double* __restrict__ pbuf) {
    __shared__ double Sl[CH][B_SZ + 1];  // transposed [m][b]; +1 pad
    __shared__ double Wl[TN][CH];
    const int tid  = threadIdx.x;
    const int nblk = blockIdx.x;   // 0..127
    const int ks   = blockIdx.y;   // 0..1
    const int n0   = nblk * TN;
    const int k0   = ks * KSL;
    const int tx   = tid & 31;     // b and b+32
    const int ty   = tid >> 5;     // 0..7 -> 4 neurons each

    double acc0[4] = {0.0, 0.0, 0.0, 0.0};
    double acc1[4] = {0.0, 0.0, 0.0, 0.0};

    for (int kk = 0; kk < KSL; kk += CH) {
        const int kb = k0 + kk;
        // stage S (64 x CH floats -> transposed doubles). 1024 float4 / 256 thr
        {
            int i = tid;
            #pragma unroll
            for (int it = 0; it < 4; ++it, i += 256) {
                int b  = i >> 4;   // 0..63
                int c4 = i & 15;   // 0..15
                float4 v = *(const float4*)(s_in + (size_t)b * N_NEUR + kb + c4 * 4);
                Sl[c4 * 4 + 0][b] = (double)v.x;
                Sl[c4 * 4 + 1][b] = (double)v.y;
                Sl[c4 * 4 + 2][b] = (double)v.z;
                Sl[c4 * 4 + 3][b] = (double)v.w;
            }
        }
        // stage W (TN x CH floats). 512 float4 / 256 thr
        {
            int i = tid;
            #pragma unroll
            for (int it = 0; it < 2; ++it, i += 256) {
                int n  = i >> 4;
                int c4 = i & 15;
                float4 v = *(const float4*)(Wres + (size_t)(n0 + n) * N_NEUR + kb + c4 * 4);
                Wl[n][c4 * 4 + 0] = (double)v.x;
                Wl[n][c4 * 4 + 1] = (double)v.y;
                Wl[n][c4 * 4 + 2] = (double)v.z;
                Wl[n][c4 * 4 + 3] = (double)v.w;
            }
        }
        __syncthreads();
        #pragma unroll 4
        for (int m = 0; m < CH; ++m) {
            double s0v = Sl[m][tx];
            double s1v = Sl[m][tx + 32];
            #pragma unroll
            for (int j = 0; j < 4; ++j) {
                double w = Wl[ty * 4 + j][m];
                acc0[j] = fma(s0v, w, acc0[j]);
                acc1[j] = fma(s1v, w, acc1[j]);
            }
        }
        __syncthreads();
    }
    double* p = pbuf + (size_t)ks * B_SZ * N_NEUR;
    #pragma unroll
    for (int j = 0; j < 4; ++j) {
        p[(size_t)tx * N_NEUR + n0 + ty * 4 + j]        = acc0[j];
        p[(size_t)(tx + 32) * N_NEUR + n0 + ty * 4 + j] = acc1[j];
    }
}

// ---------------- Kernel B: LIF update + spike ----------------
__global__ __launch_bounds__(256) void kernB(const double* __restrict__ pbuf,
                                             const float* __restrict__ x,
                                             const float* __restrict__ Win,
                                             double* __restrict__ vr,
                                             float* __restrict__ s_out,
                                             int t, int use_pbuf) {
    int idx = blockIdx.x * 256 + threadIdx.x;   // b*4096 + n
    int b = idx >> 12;
    int n = idx & 4095;
    double cur = (double)x[b * T_STEPS + t] * (double)Win[n];
    if (use_pbuf) cur += pbuf[idx] + pbuf[(size_t)B_SZ * N_NEUR + idx];
    double v = 0.9 * vr[idx] + cur;
    bool sp = (v >= 1.0);
    vr[idx] = sp ? 0.0 : v;
    s_out[idx] = sp ? 1.0f : 0.0f;
}

// ---------------- Kernel C: classifier LIF readout ----------------
__global__ __launch_bounds__(256) void kernC(const float* __restrict__ s_in,
                                             const float* __restrict__ Wout,
                                             double* __restrict__ vc,
                                             double* __restrict__ counts) {
    int b = blockIdx.x;
    int tid = threadIdx.x;
    double part[N_CLS];
    #pragma unroll
    for (int c = 0; c < N_CLS; ++c) part[c] = 0.0;
    for (int n = tid; n < N_NEUR; n += 256) {
        double s = (double)s_in[(size_t)b * N_NEUR + n];
        #pragma unroll
        for (int c = 0; c < N_CLS; ++c)
            part[c] = fma(s, (double)Wout[c * N_NEUR + n], part[c]);
    }
    __shared__ double red[4][N_CLS];
    int lane = tid & 63, wv = tid >> 6;
    #pragma unroll
    for (int c = 0; c < N_CLS; ++c) {
        double v = part[c];
        for (int off = 32; off > 0; off >>= 1)
            v += __shfl_down(v, off, 64);
        if (lane == 0) red[wv][c] = v;
    }
    __syncthreads();
    if (tid < N_CLS) {
        double tot = red[0][tid] + red[1][tid] + red[2][tid] + red[3][tid];
        double v = 0.9 * vc[b * N_CLS + tid] + tot;
        bool sp = (v >= 1.0);
        vc[b * N_CLS + tid] = sp ? 0.0 : v;
        if (sp) counts[b * N_CLS + tid] += 1.0;
    }
}

// ---------------- Kernel D: counts -> fp32 out ----------------
__global__ void kernD(const double* __restrict__ counts, float* __restrict__ out) {
    int i = blockIdx.x * blockDim.x + threadIdx.x;
    if (i < B_SZ * N_CLS) out[i] = (float)counts[i];
}

extern "C" void kernel_launch(void* const* d_in, const int* in_sizes, int n_in,
                              void* d_out, int out_size, void* d_ws, size_t ws_size,
                              hipStream_t stream) {
    const float* x    = (const float*)d_in[0];
    const float* Win  = (const float*)d_in[1];
    const float* Wres = (const float*)d_in[2];
    const float* Wout = (const float*)d_in[3];
    float* out = (float*)d_out;

    // workspace layout (~8 MiB)
    double* vr     = (double*)d_ws;                          // 64*4096 dbl
    double* pbuf   = vr + (size_t)B_SZ * N_NEUR;             // 2*64*4096 dbl
    float*  s0     = (float*)(pbuf + 2ull * B_SZ * N_NEUR);  // 64*4096 f32
    float*  s1     = s0 + (size_t)B_SZ * N_NEUR;             // 64*4096 f32
    double* vc     = (double*)(s1 + (size_t)B_SZ * N_NEUR);  // 640 dbl
    double* counts = vc + B_SZ * N_CLS;                      // 640 dbl

    hipMemsetAsync(vr, 0, (size_t)B_SZ * N_NEUR * sizeof(double), stream);
    hipMemsetAsync(vc, 0, 2ull * B_SZ * N_CLS * sizeof(double), stream);

    const int nelem = B_SZ * N_NEUR;
    // t = 0: zero spikes -> no recurrent GEMM
    kernB<<<dim3(nelem / 256), 256, 0, stream>>>(pbuf, x, Win, vr, s0, 0, 0);
    kernC<<<dim3(B_SZ), 256, 0, stream>>>(s0, Wout, vc, counts);
    for (int t = 1; t < T_STEPS; ++t) {
        const float* sp = (t & 1) ? s0 : s1;  // spikes of t-1
        float*       sn = (t & 1) ? s1 : s0;  // spikes of t
        kernA<<<dim3(128, 2), 256, 0, stream>>>(Wres, sp, pbuf);
        kernB<<<dim3(nelem / 256), 256, 0, stream>>>(pbuf, x, Win, vr, sn, t, 1);
        kernC<<<dim3(B_SZ), 256, 0, stream>>>(sn, Wout, vc, counts);
    }
    kernD<<<dim3(3), 256, 0, stream>>>(counts, out);
}

// Round 2
// 11836.124 us; speedup vs baseline: 1.3256x; 1.3256x over previous
//
#include <hip/hip_runtime.h>

#define N_NEUR 4096
#define B_SZ   64
#define T_STEPS 128
#define N_CLS  10
#define CH 64

typedef double d2 __attribute__((ext_vector_type(2)));

// ---------------- Kernel A: fp64 partial GEMM, broadcast-W structure ----------------
// pbuf[ks][n][b] = sum_{m in K-slice} sT[m][b] * Wres[n][m]
// WG: 256 threads = 64 b  x TNW n, thread tile 2b x NPT n.
template<int TNW, int KSP>
__global__ __launch_bounds__(256) void kernA(const float* __restrict__ Wres,
                                             const float* __restrict__ sT,   // [m][b] fp32
                                             double* __restrict__ pbuf) {    // [ks][n][b]
    constexpr int KSL  = N_NEUR / KSP;
    constexpr int NPT  = TNW / 8;                 // n per thread
    constexpr int WREG = TNW / 16;                // float4 per thread for W staging
    constexpr int RSH  = (TNW == 64 ? 2 : 3);     // W-staging row shift
    constexpr int CM   = (TNW == 64 ? 3 : 7);     // W-staging col mask

    __shared__ double Sl[CH][B_SZ];               // [m][b], linear
    __shared__ double Wl[CH][TNW];                // [m][n], transposed

    const int tid = threadIdx.x;
    const int n0  = blockIdx.x * TNW;
    const int k0  = blockIdx.y * KSL;
    const int bb  = tid & 31;
    const int ng  = tid >> 5;                     // 0..7
    const int nt  = ng * NPT;
    const int wr  = tid >> RSH;                   // W staging row (n within tile)
    const int wcb = tid & CM;                     // W staging col4 base

    double acc0[NPT], acc1[NPT];
    #pragma unroll
    for (int j = 0; j < NPT; ++j) { acc0[j] = 0.0; acc1[j] = 0.0; }

    float4 sreg[4];
    float4 wreg[WREG];

    const float* sbase = sT + (size_t)k0 * B_SZ;
    // prefetch chunk 0
    #pragma unroll
    for (int j = 0; j < 4; ++j)
        sreg[j] = *(const float4*)(sbase + (size_t)(tid + 256 * j) * 4);
    #pragma unroll
    for (int j = 0; j < WREG; ++j) {
        int c4 = wcb + (CM + 1) * j;
        wreg[j] = *(const float4*)(Wres + (size_t)(n0 + wr) * N_NEUR + k0 + c4 * 4);
    }

    for (int c = 0; c < KSL / CH; ++c) {
        __syncthreads();
        // stage S: linear [m][b] doubles
        #pragma unroll
        for (int j = 0; j < 4; ++j) {
            double* d = &Sl[0][0] + (size_t)(tid + 256 * j) * 4;
            d[0] = (double)sreg[j].x; d[1] = (double)sreg[j].y;
            d[2] = (double)sreg[j].z; d[3] = (double)sreg[j].w;
        }
        // stage W transposed: Wl[m][n]
        #pragma unroll
        for (int j = 0; j < WREG; ++j) {
            int c4 = wcb + (CM + 1) * j;
            Wl[c4 * 4 + 0][wr] = (double)wreg[j].x;
            Wl[c4 * 4 + 1][wr] = (double)wreg[j].y;
            Wl[c4 * 4 + 2][wr] = (double)wreg[j].z;
            Wl[c4 * 4 + 3][wr] = (double)wreg[j].w;
        }
        __syncthreads();
        if (c + 1 < KSL / CH) {
            const float* sb2 = sbase + (size_t)(c + 1) * CH * B_SZ;
            #pragma unroll
            for (int j = 0; j < 4; ++j)
                sreg[j] = *(const float4*)(sb2 + (size_t)(tid + 256 * j) * 4);
            const int kb = k0 + (c + 1) * CH;
            #pragma unroll
            for (int j = 0; j < WREG; ++j) {
                int c4 = wcb + (CM + 1) * j;
                wreg[j] = *(const float4*)(Wres + (size_t)(n0 + wr) * N_NEUR + kb + c4 * 4);
            }
        }
        #pragma unroll 4
        for (int m = 0; m < CH; ++m) {
            double s0 = Sl[m][bb];
            double s1 = Sl[m][bb + 32];
            const d2* wp = (const d2*)(&Wl[m][nt]);
            #pragma unroll
            for (int j2 = 0; j2 < NPT / 2; ++j2) {
                d2 w = wp[j2];
                acc0[2 * j2]     = fma(s0, w.x, acc0[2 * j2]);
                acc0[2 * j2 + 1] = fma(s0, w.y, acc0[2 * j2 + 1]);
                acc1[2 * j2]     = fma(s1, w.x, acc1[2 * j2]);
                acc1[2 * j2 + 1] = fma(s1, w.y, acc1[2 * j2 + 1]);
            }
        }
    }
    double* p = pbuf + (size_t)blockIdx.y * B_SZ * N_NEUR;
    #pragma unroll
    for (int j = 0; j < NPT; ++j) {
        p[(size_t)(n0 + nt + j) * B_SZ + bb]      = acc0[j];
        p[(size_t)(n0 + nt + j) * B_SZ + bb + 32] = acc1[j];
    }
}

// ---------------- Kernel B: reduce partials + LIF + transposed spike write ----------------
__global__ __launch_bounds__(256) void kernB(const double* __restrict__ pbuf,
                                             const float* __restrict__ x,
                                             const float* __restrict__ Win,
                                             double* __restrict__ vr,
                                             float* __restrict__ sT,      // [n][b] fp32
                                             int t, int nsl) {
    int idx = blockIdx.x * 256 + threadIdx.x;    // n*64 + b
    int b = idx & 63;
    int n = idx >> 6;
    double cur = (double)x[b * T_STEPS + t] * (double)Win[n];
    for (int s = 0; s < nsl; ++s)
        cur += pbuf[(size_t)s * ((size_t)B_SZ * N_NEUR) + idx];
    double v = 0.9 * vr[idx] + cur;
    bool sp = (v >= 1.0);
    vr[idx] = sp ? 0.0 : v;
    sT[idx] = sp ? 1.0f : 0.0f;
}

// ---------------- Kernel C: classifier LIF readout ----------------
__global__ __launch_bounds__(256) void kernC(const float* __restrict__ sT,   // [m][b]
                                             const float* __restrict__ Wout,
                                             double* __restrict__ vc,
                                             double* __restrict__ counts) {
    int b = blockIdx.x;
    int tid = threadIdx.x;
    double part[N_CLS];
    #pragma unroll
    for (int c = 0; c < N_CLS; ++c) part[c] = 0.0;
    for (int m = tid; m < N_NEUR; m += 256) {
        double s = (double)sT[(size_t)m * B_SZ + b];
        #pragma unroll
        for (int c = 0; c < N_CLS; ++c)
            part[c] = fma(s, (double)Wout[c * N_NEUR + m], part[c]);
    }
    __shared__ double red[4][N_CLS];
    int lane = tid & 63, wv = tid >> 6;
    #pragma unroll
    for (int c = 0; c < N_CLS; ++c) {
        double v = part[c];
        for (int off = 32; off > 0; off >>= 1)
            v += __shfl_down(v, off, 64);
        if (lane == 0) red[wv][c] = v;
    }
    __syncthreads();
    if (tid < N_CLS) {
        double tot = red[0][tid] + red[1][tid] + red[2][tid] + red[3][tid];
        double v = 0.9 * vc[b * N_CLS + tid] + tot;
        bool sp = (v >= 1.0);
        vc[b * N_CLS + tid] = sp ? 0.0 : v;
        if (sp) counts[b * N_CLS + tid] += 1.0;
    }
}

// ---------------- Kernel D: counts -> fp32 out ----------------
__global__ void kernD(const double* __restrict__ counts, float* __restrict__ out) {
    int i = blockIdx.x * blockDim.x + threadIdx.x;
    if (i < B_SZ * N_CLS) out[i] = (float)counts[i];
}

extern "C" void kernel_launch(void* const* d_in, const int* in_sizes, int n_in,
                              void* d_out, int out_size, void* d_ws, size_t ws_size,
                              hipStream_t stream) {
    const float* x    = (const float*)d_in[0];
    const float* Win  = (const float*)d_in[1];
    const float* Wres = (const float*)d_in[2];
    const float* Wout = (const float*)d_in[3];
    float* out = (float*)d_out;

    const size_t NB = (size_t)B_SZ * N_NEUR;     // 262144
    char* w = (char*)d_ws;
    double* vr     = (double*)w;                 w += NB * sizeof(double);       // 2 MB
    float*  s0     = (float*)w;                  w += NB * sizeof(float);        // 1 MB
    float*  s1     = (float*)w;                  w += NB * sizeof(float);        // 1 MB
    double* vc     = (double*)w;                 w += (size_t)B_SZ * N_CLS * sizeof(double);
    double* counts = (double*)w;                 w += (size_t)B_SZ * N_CLS * sizeof(double);
    double* pbuf   = (double*)w;                 // 4 or 2 slices x 2 MB

    size_t fixed = (size_t)(w - (char*)d_ws);
    int ksp = (ws_size >= fixed + 4 * NB * sizeof(double)) ? 4 : 2;

    hipMemsetAsync(vr, 0, NB * sizeof(double), stream);
    hipMemsetAsync(vc, 0, 2ull * B_SZ * N_CLS * sizeof(double), stream);

    // t = 0: zero spikes -> no recurrent GEMM
    kernB<<<dim3(NB / 256), 256, 0, stream>>>(pbuf, x, Win, vr, s0, 0, 0);
    kernC<<<dim3(B_SZ), 256, 0, stream>>>(s0, Wout, vc, counts);
    for (int t = 1; t < T_STEPS; ++t) {
        const float* sp = (t & 1) ? s0 : s1;  // spikes of t-1
        float*       sn = (t & 1) ? s1 : s0;  // spikes of t
        if (ksp == 4)
            kernA<64, 4><<<dim3(N_NEUR / 64, 4), 256, 0, stream>>>(Wres, sp, pbuf);
        else
            kernA<32, 2><<<dim3(N_NEUR / 32, 2), 256, 0, stream>>>(Wres, sp, pbuf);
        kernB<<<dim3(NB / 256), 256, 0, stream>>>(pbuf, x, Win, vr, sn, t, ksp);
        kernC<<<dim3(B_SZ), 256, 0, stream>>>(sn, Wout, vc, counts);
    }
    kernD<<<dim3(3), 256, 0, stream>>>(counts, out);
}

// Round 3
// 9883.554 us; speedup vs baseline: 1.5875x; 1.1976x over previous
//
#include <hip/hip_runtime.h>

#define N_NEUR 4096
#define B_SZ   64
#define T_STEPS 128
#define N_CLS  10
#define CH 64

typedef double d2 __attribute__((ext_vector_type(2)));

// ---------------- Kernel A: fp64 partial GEMM ----------------
// pbuf[ks][n][b] = sum_{m in K-slice} sT[m][b] * Wres[n][m]
// WG = 256 thr = 4 waves; each wave owns 16 n (2 segs x 8) x all 64 b.
// Thread tile: 2 b x 8 n. 2 WGs/CU (64 KB LDS each).
template<int KSP>
__global__ __launch_bounds__(256, 2) void kernA(const float* __restrict__ Wres,
                                                const float* __restrict__ sT,   // [m][b] fp32
                                                double* __restrict__ pbuf) {    // [ks][n][b]
    constexpr int KSL = N_NEUR / KSP;
    constexpr int NCHUNK = KSL / CH;

    __shared__ double Sl[CH][B_SZ];   // [m][b]  32 KB
    __shared__ double Wl[CH][64];     // [m][n]  32 KB (transposed for broadcast reads)

    const int tid  = threadIdx.x;
    const int n0   = blockIdx.x * 64;
    const int k0   = blockIdx.y * KSL;
    const int wave = tid >> 6;
    const int lane = tid & 63;
    const int b2   = (lane & 31) * 2;              // b, b+1
    const int nt   = wave * 16 + (lane >> 5) * 8;  // n within tile
    const int wr   = tid >> 2;                     // W staging: n row 0..63
    const int wc   = tid & 3;                      // W staging: col4 base

    double acc0[8], acc1[8];
    #pragma unroll
    for (int j = 0; j < 8; ++j) { acc0[j] = 0.0; acc1[j] = 0.0; }

    float4 sreg[4], wreg[4];
    const float* sbase = sT + (size_t)k0 * B_SZ;
    const float* wbase = Wres + (size_t)(n0 + wr) * N_NEUR + k0;

    #pragma unroll
    for (int j = 0; j < 4; ++j) {
        sreg[j] = *(const float4*)(sbase + (size_t)(tid + 256 * j) * 4);
        wreg[j] = *(const float4*)(wbase + (wc + 4 * j) * 4);
    }

    for (int c = 0; c < NCHUNK; ++c) {
        __syncthreads();
        // stage S: linear [m][b] doubles
        #pragma unroll
        for (int j = 0; j < 4; ++j) {
            double* d = &Sl[0][0] + (size_t)(tid + 256 * j) * 4;
            d[0] = (double)sreg[j].x; d[1] = (double)sreg[j].y;
            d[2] = (double)sreg[j].z; d[3] = (double)sreg[j].w;
        }
        // stage W transposed: Wl[m][n]
        #pragma unroll
        for (int j = 0; j < 4; ++j) {
            int m4 = (wc + 4 * j) * 4;
            Wl[m4 + 0][wr] = (double)wreg[j].x;
            Wl[m4 + 1][wr] = (double)wreg[j].y;
            Wl[m4 + 2][wr] = (double)wreg[j].z;
            Wl[m4 + 3][wr] = (double)wreg[j].w;
        }
        __syncthreads();
        if (c + 1 < NCHUNK) {
            const float* sb2 = sbase + (size_t)(c + 1) * CH * B_SZ;
            const float* wb2 = wbase + (c + 1) * CH;
            #pragma unroll
            for (int j = 0; j < 4; ++j) {
                sreg[j] = *(const float4*)(sb2 + (size_t)(tid + 256 * j) * 4);
                wreg[j] = *(const float4*)(wb2 + (wc + 4 * j) * 4);
            }
        }
        #pragma unroll 4
        for (int m = 0; m < CH; ++m) {
            d2 s = *(const d2*)&Sl[m][b2];
            const d2* wp = (const d2*)&Wl[m][nt];
            #pragma unroll
            for (int k = 0; k < 4; ++k) {
                d2 w = wp[k];
                acc0[2 * k]     = fma(s.x, w.x, acc0[2 * k]);
                acc0[2 * k + 1] = fma(s.x, w.y, acc0[2 * k + 1]);
                acc1[2 * k]     = fma(s.y, w.x, acc1[2 * k]);
                acc1[2 * k + 1] = fma(s.y, w.y, acc1[2 * k + 1]);
            }
        }
    }
    double* p = pbuf + (size_t)blockIdx.y * B_SZ * N_NEUR;
    #pragma unroll
    for (int j = 0; j < 8; ++j) {
        d2 v; v.x = acc0[j]; v.y = acc1[j];
        *(d2*)(p + (size_t)(n0 + nt + j) * B_SZ + b2) = v;
    }
}

// ---------------- Kernel B: reduce partials + LIF + transposed spike write ----------------
__global__ __launch_bounds__(256) void kernB(const double* __restrict__ pbuf,
                                             const float* __restrict__ x,
                                             const float* __restrict__ Win,
                                             double* __restrict__ vr,
                                             float* __restrict__ sT,      // [n][b] fp32
                                             int t, int nsl) {
    int idx = blockIdx.x * 256 + threadIdx.x;    // n*64 + b
    int b = idx & 63;
    int n = idx >> 6;
    double cur = (double)x[b * T_STEPS + t] * (double)Win[n];
    for (int s = 0; s < nsl; ++s)
        cur += pbuf[(size_t)s * ((size_t)B_SZ * N_NEUR) + idx];
    double v = 0.9 * vr[idx] + cur;
    bool sp = (v >= 1.0);
    vr[idx] = sp ? 0.0 : v;
    sT[idx] = sp ? 1.0f : 0.0f;
}

// ---------------- Kernel C: classifier LIF readout ----------------
__global__ __launch_bounds__(256) void kernC(const float* __restrict__ sT,   // [m][b]
                                             const float* __restrict__ Wout,
                                             double* __restrict__ vc,
                                             double* __restrict__ counts) {
    int b = blockIdx.x;
    int tid = threadIdx.x;
    double part[N_CLS];
    #pragma unroll
    for (int c = 0; c < N_CLS; ++c) part[c] = 0.0;
    for (int m = tid; m < N_NEUR; m += 256) {
        double s = (double)sT[(size_t)m * B_SZ + b];
        #pragma unroll
        for (int c = 0; c < N_CLS; ++c)
            part[c] = fma(s, (double)Wout[c * N_NEUR + m], part[c]);
    }
    __shared__ double red[4][N_CLS];
    int lane = tid & 63, wv = tid >> 6;
    #pragma unroll
    for (int c = 0; c < N_CLS; ++c) {
        double v = part[c];
        for (int off = 32; off > 0; off >>= 1)
            v += __shfl_down(v, off, 64);
        if (lane == 0) red[wv][c] = v;
    }
    __syncthreads();
    if (tid < N_CLS) {
        double tot = red[0][tid] + red[1][tid] + red[2][tid] + red[3][tid];
        double v = 0.9 * vc[b * N_CLS + tid] + tot;
        bool sp = (v >= 1.0);
        vc[b * N_CLS + tid] = sp ? 0.0 : v;
        if (sp) counts[b * N_CLS + tid] += 1.0;
    }
}

// ---------------- Kernel D: counts -> fp32 out ----------------
__global__ void kernD(const double* __restrict__ counts, float* __restrict__ out) {
    int i = blockIdx.x * blockDim.x + threadIdx.x;
    if (i < B_SZ * N_CLS) out[i] = (float)counts[i];
}

extern "C" void kernel_launch(void* const* d_in, const int* in_sizes, int n_in,
                              void* d_out, int out_size, void* d_ws, size_t ws_size,
                              hipStream_t stream) {
    const float* x    = (const float*)d_in[0];
    const float* Win  = (const float*)d_in[1];
    const float* Wres = (const float*)d_in[2];
    const float* Wout = (const float*)d_in[3];
    float* out = (float*)d_out;

    const size_t NB = (size_t)B_SZ * N_NEUR;     // 262144
    char* w = (char*)d_ws;
    double* vr     = (double*)w;                 w += NB * sizeof(double);       // 2 MB
    float*  s0     = (float*)w;                  w += NB * sizeof(float);        // 1 MB
    float*  s1     = (float*)w;                  w += NB * sizeof(float);        // 1 MB
    double* vc     = (double*)w;                 w += (size_t)B_SZ * N_CLS * sizeof(double);
    double* counts = (double*)w;                 w += (size_t)B_SZ * N_CLS * sizeof(double);
    double* pbuf   = (double*)w;                 // KSP slices x 2 MB

    size_t fixed = (size_t)(w - (char*)d_ws);
    int ksp = 2;
    if (ws_size >= fixed + 8 * NB * sizeof(double))      ksp = 8;
    else if (ws_size >= fixed + 4 * NB * sizeof(double)) ksp = 4;

    hipMemsetAsync(vr, 0, NB * sizeof(double), stream);
    hipMemsetAsync(vc, 0, 2ull * B_SZ * N_CLS * sizeof(double), stream);

    // t = 0: zero spikes -> no recurrent GEMM
    kernB<<<dim3(NB / 256), 256, 0, stream>>>(pbuf, x, Win, vr, s0, 0, 0);
    kernC<<<dim3(B_SZ), 256, 0, stream>>>(s0, Wout, vc, counts);
    for (int t = 1; t < T_STEPS; ++t) {
        const float* sp = (t & 1) ? s0 : s1;  // spikes of t-1
        float*       sn = (t & 1) ? s1 : s0;  // spikes of t
        if (ksp == 8)
            kernA<8><<<dim3(N_NEUR / 64, 8), 256, 0, stream>>>(Wres, sp, pbuf);
        else if (ksp == 4)
            kernA<4><<<dim3(N_NEUR / 64, 4), 256, 0, stream>>>(Wres, sp, pbuf);
        else
            kernA<2><<<dim3(N_NEUR / 64, 2), 256, 0, stream>>>(Wres, sp, pbuf);
        kernB<<<dim3(NB / 256), 256, 0, stream>>>(pbuf, x, Win, vr, sn, t, ksp);
        kernC<<<dim3(B_SZ), 256, 0, stream>>>(sn, Wout, vc, counts);
    }
    kernD<<<dim3(3), 256, 0, stream>>>(counts, out);
}

// Round 5
// 7949.017 us; speedup vs baseline: 1.9738x; 1.2434x over previous
//
#include <hip/hip_runtime.h>

#define N_NEUR 4096
#define B_SZ   64
#define T_STEPS 128
#define N_CLS  10

typedef double d4v __attribute__((ext_vector_type(4)));

// ---------------- layout probe: find consistent (A,B,D) lane maps for f64 MFMA ----------------
__global__ void kernProbe(int* __restrict__ combo_out) {
    int l = threadIdx.x;
    int best = -1;
    for (int c = 0; c < 16; ++c) {
        int amap = c & 1, bmap = (c >> 1) & 1, dmap = (c >> 2) & 3;
        int ai = amap ? (l >> 2) : (l & 15);
        int ak = amap ? (l & 3)  : (l >> 4);
        int bk = bmap ? (l & 3)  : (l >> 4);
        int bj = bmap ? (l >> 2) : (l & 15);
        double a = (double)(ai * 4 + ak + 1);     // A[i][k] = 4i+k+1 (exact ints)
        double b = (double)(bk * 16 + bj + 1);    // B[k][j] = 16k+j+1
        d4v d = {0.0, 0.0, 0.0, 0.0};
        d = __builtin_amdgcn_mfma_f64_16x16x4f64(a, b, d, 0, 0, 0);
        bool ok = true;
        #pragma unroll
        for (int r = 0; r < 4; ++r) {
            int di, dj;
            if      (dmap == 0) { di = 4 * (l >> 4) + r; dj = l & 15; }
            else if (dmap == 1) { di = l & 15; dj = 4 * (l >> 4) + r; }
            else if (dmap == 2) { di = (l >> 4) + 4 * r; dj = l & 15; }
            else                { di = l & 15; dj = (l >> 4) + 4 * r; }
            double ref = 0.0;
            for (int k = 0; k < 4; ++k)
                ref += (double)(di * 4 + k + 1) * (double)(k * 16 + dj + 1);
            ok = ok && (d[r] == ref);
        }
        unsigned long long m = __ballot(ok);
        if (m == ~0ull && best < 0) best = c;
    }
    if (l == 0) combo_out[0] = (best < 0) ? 0 : best;
}

// ---------------- transpose W [n][m] -> Wt [m][n] (fp32), once per launch ----------------
__global__ __launch_bounds__(256) void kernT(const float* __restrict__ W, float* __restrict__ Wt) {
    __shared__ float tile[32][33];
    int mb = blockIdx.x * 32;
    int nb = blockIdx.y * 32;
    int tx = threadIdx.x & 31, ty = threadIdx.x >> 5;
    #pragma unroll
    for (int r = 0; r < 32; r += 8)
        tile[ty + r][tx] = W[(size_t)(nb + ty + r) * N_NEUR + mb + tx];
    __syncthreads();
    #pragma unroll
    for (int r = 0; r < 32; r += 8)
        Wt[(size_t)(mb + ty + r) * N_NEUR + nb + tx] = tile[tx][ty + r];
}

// ---------------- t=0 init ----------------
__global__ __launch_bounds__(256) void kernI(const float* __restrict__ x,
                                             const float* __restrict__ Win,
                                             double* __restrict__ vr,
                                             float* __restrict__ sf,
                                             float* __restrict__ sT) {
    int idx = blockIdx.x * 256 + threadIdx.x;
    int b = idx & 63, n = idx >> 6;
    double v = (double)x[b * T_STEPS] * (double)Win[n];
    bool sp = (v >= 1.0);
    vr[idx] = sp ? 0.0 : v;
    float s = sp ? 1.0f : 0.0f;
    sT[idx] = s;
    sf[(size_t)(((n >> 2) * 4 + (b >> 4)) * 64) + (n & 3) * 16 + (b & 15)] = s;
}

// ---------------- fused recurrent GEMM (f64 MFMA) + LIF ----------------
// sfrag storage (fixed): sf[ ((m>>2)*4 + (b>>4))*64 + (m&3)*16 + (b&15) ]
template<bool USEWT>
__global__ __launch_bounds__(1024) void kernAB(const float* __restrict__ Wsrc,
                                               const float* __restrict__ sfp,
                                               const float* __restrict__ x,
                                               const float* __restrict__ Win,
                                               double* __restrict__ vr,
                                               float* __restrict__ sfc,
                                               float* __restrict__ sT,
                                               const int* __restrict__ combo_p,
                                               int t) {
    __shared__ double lbuf[4][16 * 64];
    const int tid  = threadIdx.x;
    const int wave = tid >> 6, lane = tid & 63;
    const int wb   = wave & 3, wq = wave >> 2;
    const int gn0  = blockIdx.x * 16;

    const int combo = combo_p[0];
    const int amap = combo & 1, bmap = (combo >> 1) & 1, dmap = (combo >> 2) & 3;
    const int ai = amap ? (lane >> 2) : (lane & 15);
    const int ak = amap ? (lane & 3)  : (lane >> 4);
    const int bk = bmap ? (lane & 3)  : (lane >> 4);
    const int bj = bmap ? (lane >> 2) : (lane & 15);

    d4v acc = {0.0, 0.0, 0.0, 0.0};
    const int q0 = wq * 256;
    const float* bp = sfp + (size_t)(q0 * 4 + wb) * 64 + bk * 16 + bj;

    #pragma unroll 4
    for (int q = 0; q < 256; ++q) {
        double a;
        if (USEWT) a = (double)Wsrc[(size_t)(4 * (q0 + q) + ak) * N_NEUR + gn0 + ai];
        else       a = (double)Wsrc[(size_t)(gn0 + ai) * N_NEUR + 4 * (q0 + q) + ak];
        double bv = (double)bp[(size_t)q * 256];
        acc = __builtin_amdgcn_mfma_f64_16x16x4f64(a, bv, acc, 0, 0, 0);
    }

    {
        const int jb = 16 * wb;
        #pragma unroll
        for (int r = 0; r < 4; ++r) {
            int di, dj;
            if      (dmap == 0) { di = 4 * (lane >> 4) + r; dj = lane & 15; }
            else if (dmap == 1) { di = lane & 15; dj = 4 * (lane >> 4) + r; }
            else if (dmap == 2) { di = (lane >> 4) + 4 * r; dj = lane & 15; }
            else                { di = lane & 15; dj = (lane >> 4) + 4 * r; }
            lbuf[wq][di * 64 + jb + dj] = acc[r];
        }
    }
    __syncthreads();

    int nl = tid >> 6, b = tid & 63;
    int n = gn0 + nl;
    size_t gidx = (size_t)n * 64 + b;
    double cur = lbuf[0][tid] + lbuf[1][tid] + lbuf[2][tid] + lbuf[3][tid]
               + (double)x[b * T_STEPS + t] * (double)Win[n];
    double v = 0.9 * vr[gidx] + cur;
    bool sp = (v >= 1.0);
    vr[gidx] = sp ? 0.0 : v;
    float s = sp ? 1.0f : 0.0f;
    sT[gidx] = s;
    sfc[(size_t)(((n >> 2) * 4 + (b >> 4)) * 64) + (n & 3) * 16 + (b & 15)] = s;
}

// ---------------- classifier LIF readout ----------------
__global__ __launch_bounds__(256) void kernC(const float* __restrict__ sT,
                                             const float* __restrict__ Wout,
                                             double* __restrict__ vc,
                                             double* __restrict__ counts) {
    int b = blockIdx.x;
    int tid = threadIdx.x;
    double part[N_CLS];
    #pragma unroll
    for (int c = 0; c < N_CLS; ++c) part[c] = 0.0;
    for (int m = tid; m < N_NEUR; m += 256) {
        double s = (double)sT[(size_t)m * B_SZ + b];
        #pragma unroll
        for (int c = 0; c < N_CLS; ++c)
            part[c] = fma(s, (double)Wout[c * N_NEUR + m], part[c]);
    }
    __shared__ double red[4][N_CLS];
    int lane = tid & 63, wv = tid >> 6;
    #pragma unroll
    for (int c = 0; c < N_CLS; ++c) {
        double v = part[c];
        for (int off = 32; off > 0; off >>= 1)
            v += __shfl_down(v, off, 64);
        if (lane == 0) red[wv][c] = v;
    }
    __syncthreads();
    if (tid < N_CLS) {
        double tot = red[0][tid] + red[1][tid] + red[2][tid] + red[3][tid];
        double v = 0.9 * vc[b * N_CLS + tid] + tot;
        bool sp = (v >= 1.0);
        vc[b * N_CLS + tid] = sp ? 0.0 : v;
        if (sp) counts[b * N_CLS + tid] += 1.0;
    }
}

__global__ void kernD(const double* __restrict__ counts, float* __restrict__ out) {
    int i = blockIdx.x * blockDim.x + threadIdx.x;
    if (i < B_SZ * N_CLS) out[i] = (float)counts[i];
}

extern "C" void kernel_launch(void* const* d_in, const int* in_sizes, int n_in,
                              void* d_out, int out_size, void* d_ws, size_t ws_size,
                              hipStream_t stream) {
    const float* x    = (const float*)d_in[0];
    const float* Win  = (const float*)d_in[1];
    const float* Wres = (const float*)d_in[2];
    const float* Wout = (const float*)d_in[3];
    float* out = (float*)d_out;

    const size_t NB = (size_t)B_SZ * N_NEUR;
    char* w = (char*)d_ws;
    double* vr     = (double*)w;  w += NB * sizeof(double);
    float*  sT     = (float*)w;   w += NB * sizeof(float);
    float*  sf0    = (float*)w;   w += NB * sizeof(float);
    float*  sf1    = (float*)w;   w += NB * sizeof(float);
    double* vc     = (double*)w;  w += (size_t)B_SZ * N_CLS * sizeof(double);
    double* counts = (double*)w;  w += (size_t)B_SZ * N_CLS * sizeof(double);
    int*    combo  = (int*)w;     w += 256;                       // flag + pad
    float*  Wt     = (float*)w;

    size_t fixed = (size_t)(w - (char*)d_ws);
    bool use_wt = (ws_size >= fixed + (size_t)N_NEUR * N_NEUR * sizeof(float));

    hipMemsetAsync(vc, 0, 2ull * B_SZ * N_CLS * sizeof(double), stream);

    kernProbe<<<dim3(1), 64, 0, stream>>>(combo);
    if (use_wt)
        kernT<<<dim3(N_NEUR / 32, N_NEUR / 32), 256, 0, stream>>>(Wres, Wt);

    kernI<<<dim3(NB / 256), 256, 0, stream>>>(x, Win, vr, sf0, sT);
    kernC<<<dim3(B_SZ), 256, 0, stream>>>(sT, Wout, vc, counts);
    for (int t = 1; t < T_STEPS; ++t) {
        const float* sp = (t & 1) ? sf0 : sf1;
        float*       sn = (t & 1) ? sf1 : sf0;
        if (use_wt)
            kernAB<true><<<dim3(N_NEUR / 16), 1024, 0, stream>>>(Wt, sp, x, Win, vr, sn, sT, combo, t);
        else
            kernAB<false><<<dim3(N_NEUR / 16), 1024, 0, stream>>>(Wres, sp, x, Win, vr, sn, sT, combo, t);
        kernC<<<dim3(B_SZ), 256, 0, stream>>>(sT, Wout, vc, counts);
    }
    kernD<<<dim3(3), 256, 0, stream>>>(counts, out);
}

// Round 6
// 5684.068 us; speedup vs baseline: 2.7603x; 1.3985x over previous
//
#include <hip/hip_runtime.h>

#define N_NEUR 4096
#define B_SZ   64
#define T_STEPS 128
#define N_CLS  10

typedef double d4v __attribute__((ext_vector_type(4)));

// ---------------- layout probe: find consistent (A,B,D) lane maps for f64 MFMA ----------------
__global__ void kernProbe(int* __restrict__ combo_out) {
    int l = threadIdx.x;
    int best = -1;
    for (int c = 0; c < 16; ++c) {
        int amap = c & 1, bmap = (c >> 1) & 1, dmap = (c >> 2) & 3;
        int ai = amap ? (l >> 2) : (l & 15);
        int ak = amap ? (l & 3)  : (l >> 4);
        int bk = bmap ? (l & 3)  : (l >> 4);
        int bj = bmap ? (l >> 2) : (l & 15);
        double a = (double)(ai * 4 + ak + 1);
        double b = (double)(bk * 16 + bj + 1);
        d4v d = {0.0, 0.0, 0.0, 0.0};
        d = __builtin_amdgcn_mfma_f64_16x16x4f64(a, b, d, 0, 0, 0);
        bool ok = true;
        #pragma unroll
        for (int r = 0; r < 4; ++r) {
            int di, dj;
            if      (dmap == 0) { di = 4 * (l >> 4) + r; dj = l & 15; }
            else if (dmap == 1) { di = l & 15; dj = 4 * (l >> 4) + r; }
            else if (dmap == 2) { di = (l >> 4) + 4 * r; dj = l & 15; }
            else                { di = l & 15; dj = (l >> 4) + 4 * r; }
            double ref = 0.0;
            for (int k = 0; k < 4; ++k)
                ref += (double)(di * 4 + k + 1) * (double)(k * 16 + dj + 1);
            ok = ok && (d[r] == ref);
        }
        unsigned long long m = __ballot(ok);
        if (m == ~0ull && best < 0) best = c;
    }
    if (l == 0) combo_out[0] = (best < 0) ? 0 : best;
}

// ---------------- pack W into A-fragment order: Wf[(stripe*1024+q)*64+lane] ----------------
__global__ __launch_bounds__(256) void kernP(const float* __restrict__ W,
                                             float* __restrict__ Wf,
                                             const int* __restrict__ combo_p) {
    const int combo = combo_p[0];
    const int amap = combo & 1;
    const int stripe = blockIdx.x;           // 0..255
    const int lane = threadIdx.x & 63;
    const int ai = amap ? (lane >> 2) : (lane & 15);
    const int ak = amap ? (lane & 3)  : (lane >> 4);
    const size_t nrow = (size_t)(stripe * 16 + ai) * N_NEUR;
    for (int q = threadIdx.x >> 6; q < 1024; q += 4)
        Wf[((size_t)stripe * 1024 + q) * 64 + lane] = W[nrow + 4 * q + ak];
}

// ---------------- t=0 init ----------------
__global__ __launch_bounds__(256) void kernI(const float* __restrict__ x,
                                             const float* __restrict__ Win,
                                             double* __restrict__ vr,
                                             float* __restrict__ sf,
                                             float* __restrict__ sT) {
    int idx = blockIdx.x * 256 + threadIdx.x;
    int b = idx & 63, n = idx >> 6;
    double v = (double)x[b * T_STEPS] * (double)Win[n];
    bool sp = (v >= 1.0);
    vr[idx] = sp ? 0.0 : v;
    float s = sp ? 1.0f : 0.0f;
    sT[idx] = s;
    sf[(size_t)(((n >> 2) * 4 + (b >> 4)) * 64) + (n & 3) * 16 + (b & 15)] = s;
}

// ---------------- fused: recurrent GEMM (f64 MFMA) + LIF  |  classifier for step t-1 ----------------
// blocks 0..255: 16-n stripe GEMM + LIF (16 waves: wq = k-quarter, wb = j-tile)
// blocks 256..319: classifier LIF for batch b = blockIdx-256, step t-1 (reads sTp)
template<bool USEWF>
__global__ __launch_bounds__(1024) void kernAB(const float* __restrict__ Wsrc,  // USEWF ? Wf : Wres[n][m]
                                               const float* __restrict__ sfp,
                                               const float* __restrict__ x,
                                               const float* __restrict__ Win,
                                               double* __restrict__ vr,
                                               float* __restrict__ sfc,
                                               float* __restrict__ sTc,
                                               const float* __restrict__ sTp,
                                               const float* __restrict__ Wout,
                                               double* __restrict__ vc,
                                               double* __restrict__ counts,
                                               const int* __restrict__ combo_p,
                                               int t) {
    __shared__ double lbuf[4][16 * 64];
    __shared__ double red[16][N_CLS];
    const int tid  = threadIdx.x;
    const int wave = tid >> 6, lane = tid & 63;

    if (blockIdx.x >= 256) {
        // ---- classifier path: step t-1, batch b ----
        const int b = blockIdx.x - 256;
        double part[N_CLS];
        #pragma unroll
        for (int c = 0; c < N_CLS; ++c) part[c] = 0.0;
        for (int m = tid; m < N_NEUR; m += 1024) {
            double s = (double)sTp[(size_t)m * B_SZ + b];
            #pragma unroll
            for (int c = 0; c < N_CLS; ++c)
                part[c] = fma(s, (double)Wout[c * N_NEUR + m], part[c]);
        }
        #pragma unroll
        for (int c = 0; c < N_CLS; ++c) {
            double v = part[c];
            for (int off = 32; off > 0; off >>= 1)
                v += __shfl_down(v, off, 64);
            if (lane == 0) red[wave][c] = v;
        }
        __syncthreads();
        if (tid < N_CLS) {
            double tot = 0.0;
            #pragma unroll
            for (int wv = 0; wv < 16; ++wv) tot += red[wv][tid];
            double v = 0.9 * vc[b * N_CLS + tid] + tot;
            bool sp = (v >= 1.0);
            vc[b * N_CLS + tid] = sp ? 0.0 : v;
            if (sp) counts[b * N_CLS + tid] += 1.0;
        }
        return;
    }

    // ---- GEMM + LIF path ----
    const int wb = wave & 3, wq = wave >> 2;
    const int gn0 = blockIdx.x * 16;
    const int combo = combo_p[0];
    const int amap = combo & 1, bmap = (combo >> 1) & 1, dmap = (combo >> 2) & 3;
    const int bk = bmap ? (lane & 3)  : (lane >> 4);
    const int bj = bmap ? (lane >> 2) : (lane & 15);

    d4v acc = {0.0, 0.0, 0.0, 0.0};
    const int q0 = wq * 256;
    const float* bp = sfp + (size_t)(q0 * 4 + wb) * 64 + bk * 16 + bj;

    if (USEWF) {
        const float* ap = Wsrc + ((size_t)blockIdx.x * 1024 + q0) * 64 + lane;
        for (int blk = 0; blk < 64; ++blk) {
            #pragma unroll
            for (int u = 0; u < 4; ++u) {
                double a  = (double)ap[u * 64];     // imm offsets 0..768 B
                double bv = (double)bp[u * 256];    // imm offsets 0..3072 B
                acc = __builtin_amdgcn_mfma_f64_16x16x4f64(a, bv, acc, 0, 0, 0);
            }
            ap += 256;
            bp += 1024;
        }
    } else {
        const int ai = amap ? (lane >> 2) : (lane & 15);
        const int ak = amap ? (lane & 3)  : (lane >> 4);
        #pragma unroll 4
        for (int q = 0; q < 256; ++q) {
            double a  = (double)Wsrc[(size_t)(gn0 + ai) * N_NEUR + 4 * (q0 + q) + ak];
            double bv = (double)bp[(size_t)q * 256];
            acc = __builtin_amdgcn_mfma_f64_16x16x4f64(a, bv, acc, 0, 0, 0);
        }
    }

    {
        const int jb = 16 * wb;
        #pragma unroll
        for (int r = 0; r < 4; ++r) {
            int di, dj;
            if      (dmap == 0) { di = 4 * (lane >> 4) + r; dj = lane & 15; }
            else if (dmap == 1) { di = lane & 15; dj = 4 * (lane >> 4) + r; }
            else if (dmap == 2) { di = (lane >> 4) + 4 * r; dj = lane & 15; }
            else                { di = lane & 15; dj = (lane >> 4) + 4 * r; }
            lbuf[wq][di * 64 + jb + dj] = acc[r];
        }
    }
    __syncthreads();

    int nl = tid >> 6, b = tid & 63;
    int n = gn0 + nl;
    size_t gidx = (size_t)n * 64 + b;
    double cur = lbuf[0][tid] + lbuf[1][tid] + lbuf[2][tid] + lbuf[3][tid]
               + (double)x[b * T_STEPS + t] * (double)Win[n];
    double v = 0.9 * vr[gidx] + cur;
    bool sp = (v >= 1.0);
    vr[gidx] = sp ? 0.0 : v;
    float s = sp ? 1.0f : 0.0f;
    sTc[gidx] = s;
    sfc[(size_t)(((n >> 2) * 4 + (b >> 4)) * 64) + (n & 3) * 16 + (b & 15)] = s;
}

// ---------------- standalone classifier (final step) ----------------
__global__ __launch_bounds__(256) void kernC(const float* __restrict__ sT,
                                             const float* __restrict__ Wout,
                                             double* __restrict__ vc,
                                             double* __restrict__ counts) {
    int b = blockIdx.x;
    int tid = threadIdx.x;
    double part[N_CLS];
    #pragma unroll
    for (int c = 0; c < N_CLS; ++c) part[c] = 0.0;
    for (int m = tid; m < N_NEUR; m += 256) {
        double s = (double)sT[(size_t)m * B_SZ + b];
        #pragma unroll
        for (int c = 0; c < N_CLS; ++c)
            part[c] = fma(s, (double)Wout[c * N_NEUR + m], part[c]);
    }
    __shared__ double red[4][N_CLS];
    int lane = tid & 63, wv = tid >> 6;
    #pragma unroll
    for (int c = 0; c < N_CLS; ++c) {
        double v = part[c];
        for (int off = 32; off > 0; off >>= 1)
            v += __shfl_down(v, off, 64);
        if (lane == 0) red[wv][c] = v;
    }
    __syncthreads();
    if (tid < N_CLS) {
        double tot = red[0][tid] + red[1][tid] + red[2][tid] + red[3][tid];
        double v = 0.9 * vc[b * N_CLS + tid] + tot;
        bool sp = (v >= 1.0);
        vc[b * N_CLS + tid] = sp ? 0.0 : v;
        if (sp) counts[b * N_CLS + tid] += 1.0;
    }
}

__global__ void kernD(const double* __restrict__ counts, float* __restrict__ out) {
    int i = blockIdx.x * blockDim.x + threadIdx.x;
    if (i < B_SZ * N_CLS) out[i] = (float)counts[i];
}

extern "C" void kernel_launch(void* const* d_in, const int* in_sizes, int n_in,
                              void* d_out, int out_size, void* d_ws, size_t ws_size,
                              hipStream_t stream) {
    const float* x    = (const float*)d_in[0];
    const float* Win  = (const float*)d_in[1];
    const float* Wres = (const float*)d_in[2];
    const float* Wout = (const float*)d_in[3];
    float* out = (float*)d_out;

    const size_t NB = (size_t)B_SZ * N_NEUR;
    char* w = (char*)d_ws;
    double* vr     = (double*)w;  w += NB * sizeof(double);
    float*  sTa    = (float*)w;   w += NB * sizeof(float);
    float*  sTb    = (float*)w;   w += NB * sizeof(float);
    float*  sf0    = (float*)w;   w += NB * sizeof(float);
    float*  sf1    = (float*)w;   w += NB * sizeof(float);
    double* vc     = (double*)w;  w += (size_t)B_SZ * N_CLS * sizeof(double);
    double* counts = (double*)w;  w += (size_t)B_SZ * N_CLS * sizeof(double);
    int*    combo  = (int*)w;     w += 256;
    float*  Wf     = (float*)w;   // 64 MB fragment-packed W

    size_t fixed = (size_t)(w - (char*)d_ws);
    bool use_wf = (ws_size >= fixed + (size_t)N_NEUR * N_NEUR * sizeof(float));

    hipMemsetAsync(vc, 0, 2ull * B_SZ * N_CLS * sizeof(double), stream);

    kernProbe<<<dim3(1), 64, 0, stream>>>(combo);
    if (use_wf)
        kernP<<<dim3(256), 256, 0, stream>>>(Wres, Wf, combo);

    kernI<<<dim3(NB / 256), 256, 0, stream>>>(x, Win, vr, sf0, sTa);
    for (int t = 1; t < T_STEPS; ++t) {
        const float* sfp = (t & 1) ? sf0 : sf1;
        float*       sfc = (t & 1) ? sf1 : sf0;
        float*       sTc = (t & 1) ? sTb : sTa;
        const float* sTp = (t & 1) ? sTa : sTb;
        if (use_wf)
            kernAB<true><<<dim3(320), 1024, 0, stream>>>(Wf, sfp, x, Win, vr, sfc, sTc, sTp,
                                                         Wout, vc, counts, combo, t);
        else
            kernAB<false><<<dim3(320), 1024, 0, stream>>>(Wres, sfp, x, Win, vr, sfc, sTc, sTp,
                                                          Wout, vc, counts, combo, t);
    }
    kernC<<<dim3(B_SZ), 256, 0, stream>>>(sTb, Wout, vc, counts);  // t = 127 (odd -> sTb)
    kernD<<<dim3(3), 256, 0, stream>>>(counts, out);
}